// Round 8
// baseline (112.729 us; speedup 1.0000x reference)
//
#include <hip/hip_runtime.h>
#include <math.h>

#define NBINS 80
#define NVERT 128
#define NRH 5
#define NDEG 6           // Taylor terms d=0..5; remainder ~1e-5 (<< f16 eps)

#define PSTR 136         // halves per P/M row; cols 0..127 data, 128..135 pad
#define DSTR 80          // halves per desc row (per nt)
#define DI   1280        // halves per desc feature slab (desc = exactly 10240 B)

#define OFF_W 6800       // w[d][vert]: 6 x 128 f16 = 1536 B at [6800,8336)
                         // (replaces the VT scratch; R8: chain1 B built in regs)
#define SLICE  10240     // per-sample LDS slice; desc overlay [0,10240) after chain1
#define WPB    4         // samples (waves) per WG; 4*10240 = 40960 B/WG
                         // -> 4 WGs/CU = 16 waves/CU in 4 WG-slots

#define NSET_C 48        // C-matrix frag sets: 16 nt x 3 ks
#define NSET_W 60        // W frag sets: 4 i x 5 tiles x 3 ks
#define WS_BYTES ((NSET_C + NSET_W) * 64 * 8 * 2)

// Same-wave LDS ordering fences (replace __syncthreads; R3 lesson):
#define LDS_ORDER() asm volatile("" ::: "memory")
#define LDS_DRAIN() asm volatile("s_waitcnt lgkmcnt(0)" ::: "memory")

typedef _Float16 half8 __attribute__((ext_vector_type(8)));
typedef float f32x4 __attribute__((ext_vector_type(4)));

// ---- prep: constant C-matrix frags + W frags in d_ws (unchanged, verified) ----
__global__ __launch_bounds__(64) void prep_frags(const float* __restrict__ Wc,
                                                 const float* __restrict__ sig_th,
                                                 _Float16* __restrict__ ws) {
    const int blk  = blockIdx.x;
    const int lane = threadIdx.x;
    constexpr float TWO_PI = 6.28318530717958647692f;
    constexpr float DLT    = TWO_PI / 16.0f;
    constexpr float LN2    = 0.69314718055994530942f;
    half8 h;
    if (blk < NSET_C) {
        constexpr float LOG2E = 1.44269504088896340736f;
        constexpr float EPSF  = 1e-5f;
        const float st = sig_th[0];
        const float Kt = -LOG2E / (st * st + EPSF);
        const int ks = blk % 3;
        const int nt = blk / 3;
        const int t  = lane & 15;
        const int q  = lane >> 4;
        #pragma unroll
        for (int j = 0; j < 8; ++j) {
            const int k = ks * 32 + q * 8 + j;     // 0..95
            const int a = k / NDEG;
            const int d = k % NDEG;
            const int m = ((a + nt) & 15) - t;
            const float s = fmaf((float)m, DLT, 0.5f * DLT);
            const float z = 2.0f * LN2 * Kt * s * (0.5f * DLT);
            float val = exp2f(Kt * s * s);
            for (int dd = 1; dd <= d; ++dd) val *= z / (float)dd;
            h[j] = (_Float16)val;
        }
    } else {
        const int e    = blk - NSET_C;
        const int ks   = e % 3;
        const int tile = (e / 3) % 5;
        const int i    = e / 15;
        const int cc   = tile * 16 + (lane & 15);
        const int bb0  = ks * 32 + (lane >> 4) * 8;
        #pragma unroll
        for (int j = 0; j < 8; ++j) {
            const int bb = bb0 + j;
            h[j] = (_Float16)((bb < NBINS) ? Wc[i * NBINS * NBINS + bb * NBINS + cc] : 0.0f);
        }
    }
    *(half8*)(ws + ((size_t)blk * 64 + lane) * 8) = h;
}

// WAVE-PER-SAMPLE, 4 samples per 256-thread WG. ZERO barriers; same-wave DS
// ordering via LDS_ORDER/LDS_DRAIN at phase boundaries (R3 lesson).
// R8 restructure: chain1's VT scratch is GONE. Compaction precomputes
// w[d][vert] = g * u^d (6 f16 rows); chain1 builds each MFMA B-frag in
// REGISTERS: lane (t,kq), tile lct covers row = lct*16+t = a_req*6+d, so
// b[j] = (bin[vert]==a_req) ? w[d][vert] : 0 over its 8 contiguous verts.
// Removes per-chunk VT zero/scatter/read round trips (~half of all DS
// traffic and ~2K serial cycles per wave) and ALL fences inside chain1 --
// the loop reads only immutable data, so the compiler can pipeline chunks.
template <int USEWS>
__global__ __launch_bounds__(256, 4) void masif_geo_conv(
    const float* __restrict__ rho_c,
    const float* __restrict__ th_c,
    const float* __restrict__ feat_g,
    const float* __restrict__ mask_g,
    const float* __restrict__ mu_rho,
    const float* __restrict__ sig_rho,
    const float* __restrict__ mu_th,
    const float* __restrict__ sig_th,
    const float* __restrict__ Wc,
    const float* __restrict__ bcv,
    const _Float16* __restrict__ ws,
    const int nsamp,
    float* __restrict__ out)
{
    const int wave = threadIdx.x >> 6;
    const int lane = threadIdx.x & 63;
    const int n    = blockIdx.x * WPB + wave; // one sample per wave

    __shared__ __align__(16) char s_raw[WPB * SLICE];

    if (n >= nsamp) return;                   // safe: no barriers anywhere

    const int t  = lane & 15;
    const int kq = lane >> 4;

    char* s_base = s_raw + wave * SLICE;      // private per-wave slice
    _Float16* s_PM = (_Float16*)(s_base);                 // P, then M
    _Float16* s_w  = (_Float16*)(s_base + OFF_W);         // w[d][vert]
    _Float16* s_d  = (_Float16*)(s_base);                 // desc overlay (late)

    constexpr float LOG2E   = 1.44269504088896340736f;
    constexpr float TWO_PI  = 6.28318530717958647692f;
    constexpr float DLT     = TWO_PI / 16.0f;
    constexpr float INV_DLT = 16.0f / TWO_PI;
    constexpr float EPSF    = 1e-5f;

    const float st = sig_th[0];
    const float Kt = -LOG2E / (st * st + EPSF);
    const float sr = sig_rho[0];
    const float Kr = -LOG2E / (sr * sr + EPSF);
    float mr[NRH];
    #pragma unroll
    for (int r = 0; r < NRH; ++r) mr[r] = mu_rho[r * 16];

    // ---- zero P + pads + w region + slack [0, 8704 B) = 544 int4.
    //      (slack keeps chain2's A1 rows 25..31 finite; their D rows are
    //      never read -- established invariant.) ----
    #pragma unroll
    for (int x = 0; x < 9; ++x) {
        const int idx = x * 64 + lane;
        if (idx < 544) ((int4*)s_PM)[idx] = make_int4(0, 0, 0, 0);
    }
    LDS_ORDER();                                  // [1] zero before compaction

    // ---- compaction: 128 verts in 2 rounds of 64, wave-local ballot ----
    int nc = 0;
    #pragma unroll
    for (int h = 0; h < 2; ++h) {
        const int v     = h * 64 + lane;
        const float mv   = mask_g[n * NVERT + v];
        const float thv  = th_c[n * NVERT + v];
        const float rhov = rho_c[n * NVERT + v];
        const float4 f4  = *(const float4*)&feat_g[(n * NVERT + v) * 4];
        const bool act = (mv != 0.0f);
        const unsigned long long bal = __ballot(act);
        if (act) {
            const int pos = nc + (int)__popcll(bal & ((1ull << lane) - 1ull));
            int aa = (int)floorf(thv * INV_DLT);
            aa = aa > 15 ? 15 : (aa < 0 ? 0 : aa);
            const float rvp = thv - (float)aa * DLT - 0.5f * DLT;   // [-DLT/2, DLT/2)
            float R[NRH];
            #pragma unroll
            for (int r = 0; r < NRH; ++r) {
                const float dr = rhov - mr[r];
                R[r] = mv * exp2f(Kr * dr * dr);
            }
            const float fv[4] = {f4.x, f4.y, f4.z, f4.w};
            #pragma unroll
            for (int f = 0; f < 4; ++f) {
                #pragma unroll
                for (int r = 0; r < 4; ++r)
                    s_PM[(f * 4 + r) * PSTR + pos] = (_Float16)(fv[f] * R[r]);
                s_PM[(16 + f) * PSTR + pos] = (_Float16)(fv[f] * R[4]);
            }
            #pragma unroll
            for (int r = 0; r < NRH; ++r)
                s_PM[(20 + r) * PSTR + pos] = (_Float16)R[r];
            // bin id byte (P pad rows 16..23)
            ((char*)s_PM)[(16 + (pos >> 4)) * 2 * PSTR + 256 + (pos & 15)] = (char)aa;
            // w[d][pos] = g * u^d, d = 0..5 (same f16 values the VT build made)
            const float gth = exp2f(Kt * rvp * rvp);
            const float uu  = rvp * (2.0f * INV_DLT);
            float wacc = gth;
            #pragma unroll
            for (int d = 0; d < 6; ++d) {
                s_w[d * 128 + pos] = (_Float16)wacc;
                wacc *= uu;
            }
        }
        nc += (int)__popcll(bal);
    }
    LDS_DRAIN();                                  // [2] P/w/bins complete

    // ---- chain 1: M = P x B over chunks of 32 verts; B built in registers.
    //      Tile lct covers rows lct*16+t = a_req*6 + d. Per chunk: 2 A-frag
    //      b128 reads + 1 b64 bin read + 6 w half8 reads; no LDS writes. ----
    f32x4 M0[6], M1[6];
    #pragma unroll
    for (int cb = 0; cb < 6; ++cb) {
        M0[cb] = (f32x4){0.f, 0.f, 0.f, 0.f};
        M1[cb] = (f32x4){0.f, 0.f, 0.f, 0.f};
    }
    int areq[6], woff[6];
    #pragma unroll
    for (int lct = 0; lct < 6; ++lct) {
        const int row = lct * 16 + t;
        areq[lct] = row / 6;
        woff[lct] = (row % 6) * 128 + kq * 8;     // halves into s_w
    }
    const int nch = (nc + 31) >> 5;
    #pragma unroll 2
    for (int ch = 0; ch < nch; ++ch) {
        const half8 av0 = *(const half8*)(s_PM + t * PSTR + ch * 32 + kq * 8);
        const half8 av1 = *(const half8*)(s_PM + (16 + t) * PSTR + ch * 32 + kq * 8);
        // this lane's 8 verts: ch*32 + kq*8 + [0..8) -- bin ids as one b64
        const unsigned long long ab = *(const unsigned long long*)
            ((const char*)s_PM + (16 + ch * 2 + (kq >> 1)) * 2 * PSTR + 256 + (kq & 1) * 8);
        int aj[8];
        #pragma unroll
        for (int j = 0; j < 8; ++j) aj[j] = (int)((ab >> (8 * j)) & 0xffull);
        #pragma unroll
        for (int lct = 0; lct < 6; ++lct) {
            const half8 wv = *(const half8*)(s_w + woff[lct] + ch * 32);
            half8 b;
            #pragma unroll
            for (int j = 0; j < 8; ++j)
                b[j] = (aj[j] == areq[lct]) ? wv[j] : (_Float16)0.0f;
            __builtin_amdgcn_s_setprio(1);
            M0[lct] = __builtin_amdgcn_mfma_f32_16x16x32_f16(av0, b, M0[lct], 0, 0, 0);
            M1[lct] = __builtin_amdgcn_mfma_f32_16x16x32_f16(av1, b, M1[lct], 0, 0, 0);
            __builtin_amdgcn_s_setprio(0);
        }
    }
    LDS_ORDER();                                  // chain1 reads before M overwrite

    // ---- M (both tiles) -> LDS f16 A-layout. D: col=t, row=kq*4+reg ----
    #pragma unroll
    for (int cb = 0; cb < 6; ++cb) {
        const int md = cb * 16 + t;
        #pragma unroll
        for (int reg = 0; reg < 4; ++reg) {
            const int lr = kq * 4 + reg;
            s_PM[lr * PSTR + md] = (_Float16)M0[cb][reg];
            if (lr < 9)
                s_PM[(16 + lr) * PSTR + md] = (_Float16)M1[cb][reg];
        }
    }
    LDS_DRAIN();                                  // [3] M complete before A-frag reads

    // ---- chain2 A-frags -> regs (before desc overlays P/M) ----
    half8 A0[3], A1[3];
    #pragma unroll
    for (int ks = 0; ks < 3; ++ks) {
        A0[ks] = *(const half8*)(s_PM + t * PSTR + ks * 32 + kq * 8);
        A1[ks] = *(const half8*)(s_PM + (16 + t) * PSTR + ks * 32 + kq * 8);
    }
    LDS_ORDER();                                  // [4] A-frag reads before desc overlay

    // ---- chain 2: g-loop, unroll 2 (next g's ws loads pipeline under this
    //      g's MFMAs+epilogue); fused epilogue ----
    const half8* wsv = (const half8*)ws;
    #pragma unroll 2
    for (int g = 0; g < 4; ++g) {
        f32x4 C0g[4], C1g[4];
        #pragma unroll
        for (int j = 0; j < 4; ++j) {
            C0g[j] = (f32x4){0.f, 0.f, 0.f, 0.f};
            C1g[j] = (f32x4){0.f, 0.f, 0.f, 0.f};
        }
        #pragma unroll
        for (int j = 0; j < 4; ++j) {
            const int nt = g * 4 + j;
            half8 b0, b1, b2;
            if (USEWS) {
                b0 = wsv[(size_t)((nt * 3 + 0) * 64 + lane)];
                b1 = wsv[(size_t)((nt * 3 + 1) * 64 + lane)];
                b2 = wsv[(size_t)((nt * 3 + 2) * 64 + lane)];
            } else {
                #pragma unroll
                for (int ks = 0; ks < 3; ++ks) {
                    half8 bb;
                    #pragma unroll
                    for (int jj = 0; jj < 8; ++jj) {
                        const int k = ks * 32 + kq * 8 + jj;
                        const int a = k / NDEG, d = k % NDEG;
                        const int mm = ((a + nt) & 15) - t;
                        const float s = fmaf((float)mm, DLT, 0.5f * DLT);
                        const float z = 2.0f * 0.69314718055994530942f * Kt * s * (0.5f * DLT);
                        float val = exp2f(Kt * s * s);
                        for (int dd = 1; dd <= d; ++dd) val *= z / (float)dd;
                        bb[jj] = (_Float16)val;
                    }
                    if (ks == 0) b0 = bb; else if (ks == 1) b1 = bb; else b2 = bb;
                }
            }
            __builtin_amdgcn_s_setprio(1);
            C0g[j] = __builtin_amdgcn_mfma_f32_16x16x32_f16(A0[0], b0, C0g[j], 0, 0, 0);
            C1g[j] = __builtin_amdgcn_mfma_f32_16x16x32_f16(A1[0], b0, C1g[j], 0, 0, 0);
            C0g[j] = __builtin_amdgcn_mfma_f32_16x16x32_f16(A0[1], b1, C0g[j], 0, 0, 0);
            C1g[j] = __builtin_amdgcn_mfma_f32_16x16x32_f16(A1[1], b1, C1g[j], 0, 0, 0);
            C0g[j] = __builtin_amdgcn_mfma_f32_16x16x32_f16(A0[2], b2, C0g[j], 0, 0, 0);
            C1g[j] = __builtin_amdgcn_mfma_f32_16x16x32_f16(A1[2], b2, C1g[j], 0, 0, 0);
            __builtin_amdgcn_s_setprio(0);
        }
        // fused epilogue: desc = num/(den+eps) -> s_d[i][nt][bb]
        #pragma unroll
        for (int j = 0; j < 4; ++j) {
            const int nt = g * 4 + j;
            float den[5], inv[5];
            #pragma unroll
            for (int r = 0; r < 4; ++r) den[r] = __shfl(C1g[j][r], 16 + t);
            den[4] = __shfl(C1g[j][0], 32 + t);
            #pragma unroll
            for (int r = 0; r < NRH; ++r) {
                const float x = den[r] + EPSF;
                float vv = __builtin_amdgcn_rcpf(x);
                inv[r] = vv * (2.0f - x * vv);
            }
            #pragma unroll
            for (int reg = 0; reg < 4; ++reg)
                s_d[kq * DI + nt * DSTR + reg * 16 + t] =
                    (_Float16)(C0g[j][reg] * inv[reg]);
            if (kq == 0) {
                #pragma unroll
                for (int reg = 0; reg < 4; ++reg)
                    s_d[reg * DI + nt * DSTR + 64 + t] =
                        (_Float16)(C1g[j][reg] * inv[4]);
            }
        }
    }
    LDS_DRAIN();                                  // [5] desc complete before phase2 reads

    // ---- phase 2: i-loop, unroll 2 (pipeline W/desc loads across i) ----
    #pragma unroll 2
    for (int i = 0; i < 4; ++i) {
        f32x4 Cc[5];
        #pragma unroll
        for (int tl = 0; tl < 5; ++tl) Cc[tl] = (f32x4){0.f, 0.f, 0.f, 0.f};
        #pragma unroll
        for (int ks = 0; ks < 3; ++ks) {
            const half8 a = *(const half8*)(s_d + i * DI + t * DSTR + ks * 32 + kq * 8);
            half8 b[5];
            #pragma unroll
            for (int tl = 0; tl < 5; ++tl) {
                if (USEWS) {
                    b[tl] = wsv[(size_t)((NSET_C + (i * 5 + tl) * 3 + ks) * 64 + lane)];
                } else {
                    const int cc  = tl * 16 + t;
                    const int bb0 = ks * 32 + kq * 8;
                    #pragma unroll
                    for (int j = 0; j < 8; ++j) {
                        const int bb = bb0 + j;
                        b[tl][j] = (_Float16)((bb < NBINS) ? Wc[i * NBINS * NBINS + bb * NBINS + cc] : 0.0f);
                    }
                }
            }
            __builtin_amdgcn_s_setprio(1);
            #pragma unroll
            for (int tl = 0; tl < 5; ++tl)
                Cc[tl] = __builtin_amdgcn_mfma_f32_16x16x32_f16(a, b[tl], Cc[tl], 0, 0, 0);
            __builtin_amdgcn_s_setprio(0);
        }
        #pragma unroll
        for (int tl = 0; tl < 5; ++tl) {
            float mx = fmaxf(fmaxf(Cc[tl][0], Cc[tl][1]), fmaxf(Cc[tl][2], Cc[tl][3]));
            mx = fmaxf(mx, __shfl_xor(mx, 16));
            mx = fmaxf(mx, __shfl_xor(mx, 32));
            if (lane < 16) {
                const int cc = tl * 16 + lane;
                out[(size_t)n * 320 + i * NBINS + cc] =
                    fmaxf(mx + bcv[i * NBINS + cc], 0.0f);
            }
        }
    }
}

extern "C" void kernel_launch(void* const* d_in, const int* in_sizes, int n_in,
                              void* d_out, int out_size, void* d_ws, size_t ws_size,
                              hipStream_t stream) {
    const float* rho   = (const float*)d_in[0];
    const float* theta = (const float*)d_in[1];
    const float* feat  = (const float*)d_in[2];
    const float* mask  = (const float*)d_in[3];
    const float* mu_r  = (const float*)d_in[4];
    const float* sg_r  = (const float*)d_in[5];
    const float* mu_t  = (const float*)d_in[6];
    const float* sg_t  = (const float*)d_in[7];
    const float* W     = (const float*)d_in[8];
    const float* bconv = (const float*)d_in[9];
    float* outp = (float*)d_out;

    const int nsamp = in_sizes[0] / NVERT;
    const int ngrid = (nsamp + WPB - 1) / WPB;    // 4 samples per WG
    const int useWs = (ws_size >= (size_t)WS_BYTES) ? 1 : 0;
    _Float16* wsh = (_Float16*)d_ws;

    if (useWs) {
        prep_frags<<<NSET_C + NSET_W, 64, 0, stream>>>(W, sg_t, wsh);
        masif_geo_conv<1><<<ngrid, 64 * WPB, 0, stream>>>(
            rho, theta, feat, mask, mu_r, sg_r, mu_t, sg_t, W, bconv,
            wsh, nsamp, outp);
    } else {
        masif_geo_conv<0><<<ngrid, 64 * WPB, 0, stream>>>(
            rho, theta, feat, mask, mu_r, sg_r, mu_t, sg_t, W, bconv,
            wsh, nsamp, outp);
    }
}